// Round 1
// baseline (544.854 us; speedup 1.0000x reference)
//
#include <hip/hip_runtime.h>
#include <math.h>

#define D 1024
#define LSEQ 256
#define NB 128
constexpr float SCALE = 0.03125f; // 1/sqrt(1024)

// out[b] = dot(A[b, 0:1024], vec)
__global__ void dot128_kernel(const float* __restrict__ A,
                              const float* __restrict__ vec,
                              float* __restrict__ out) {
  int b = blockIdx.x;
  int lane = threadIdx.x; // 64 threads
  const float* row = A + (size_t)b * D;
  float s = 0.f;
  #pragma unroll
  for (int i = 0; i < D; i += 64) s = fmaf(row[i + lane], vec[i + lane], s);
  #pragma unroll
  for (int off = 32; off; off >>= 1) s += __shfl_xor(s, off);
  if (lane == 0) out[b] = s;
}

// C[m,n] += sum_k A[m,k]*Wmat ; M=128, N=1024, K=1024.
// FORM 0: Wmat = W[n,k] (dot W rows) ; FORM 1: Wmat = W[k,n]
// BIASMODE 0: none, 1: +bias[n], 2: +rowScale[m]*bias[n]   (only ksplit block 0 adds)
// grid (64, 4): 16 n per block, K split in 4. C must be pre-zeroed (atomicAdd).
template<int FORM, int BIASMODE>
__global__ __launch_bounds__(256) void gemm128_kernel(
    const float* __restrict__ A, size_t lda,
    const float* __restrict__ W,
    const float* __restrict__ bias,
    const float* __restrict__ rowScale,
    float* __restrict__ C) {
  __shared__ float As[32][132];
  __shared__ float Ws[32][20];
  const int nbase = blockIdx.x * 16;
  const int k0 = blockIdx.y * 256;
  const int tid = threadIdx.x;
  const int tm = tid & 31;   // m-quad: m = tm*4 + i
  const int tn = tid >> 5;   // n-pair: n = nbase + tn*2 + j
  float acc[4][2] = {{0.f,0.f},{0.f,0.f},{0.f,0.f},{0.f,0.f}};

  for (int it = 0; it < 8; ++it) {
    const int kc = k0 + it * 32;
    #pragma unroll
    for (int i = 0; i < 4; ++i) {
      int f = tid + i * 256;           // float4 id, 0..1023
      int m = f >> 3, kq = f & 7;
      float4 v = *(const float4*)(A + (size_t)m * lda + kc + kq * 4);
      As[kq*4+0][m] = v.x; As[kq*4+1][m] = v.y;
      As[kq*4+2][m] = v.z; As[kq*4+3][m] = v.w;
    }
    if (tid < 128) {
      if (FORM == 0) {
        int n = tid >> 3, kq = tid & 7;
        float4 v = *(const float4*)(W + (size_t)(nbase + n) * D + kc + kq * 4);
        Ws[kq*4+0][n] = v.x; Ws[kq*4+1][n] = v.y;
        Ws[kq*4+2][n] = v.z; Ws[kq*4+3][n] = v.w;
      } else {
        int kk = tid >> 2, nq = tid & 3;
        float4 v = *(const float4*)(W + (size_t)(kc + kk) * D + nbase + nq * 4);
        *(float4*)&Ws[kk][nq * 4] = v;
      }
    }
    __syncthreads();
    #pragma unroll
    for (int kk = 0; kk < 32; ++kk) {
      float4 a4 = *(const float4*)&As[kk][tm * 4];
      float2 w2 = *(const float2*)&Ws[kk][tn * 2];
      float av[4] = {a4.x, a4.y, a4.z, a4.w};
      #pragma unroll
      for (int i = 0; i < 4; ++i) {
        acc[i][0] = fmaf(av[i], w2.x, acc[i][0]);
        acc[i][1] = fmaf(av[i], w2.y, acc[i][1]);
      }
    }
    __syncthreads();
  }
  #pragma unroll
  for (int i = 0; i < 4; ++i) {
    int m = tm * 4 + i;
    #pragma unroll
    for (int j = 0; j < 2; ++j) {
      int n = nbase + tn * 2 + j;
      float v = acc[i][j];
      if (blockIdx.y == 0) {
        if (BIASMODE == 1) v += bias[n];
        else if (BIASMODE == 2) v += rowScale[m] * bias[n];
      }
      atomicAdd(&C[(size_t)m * D + n], v);
    }
  }
}

// Per (chunk,b): attA0[c] = SCALE*(p[b].cap[b,c] + qdot[b]) for 64 c's,
// accumulate nOut[b,:] += sum_c attA0[c]*cap[b,c,:], sA[b] += sum_c attA0[c].
// grid (4, 128), 256 threads (4 waves, wave handles c%4==wid).
__global__ __launch_bounds__(256) void cap_stream_kernel(
    const float* __restrict__ cap, const float* __restrict__ p,
    const float* __restrict__ qdot, float* __restrict__ nOut,
    float* __restrict__ sA) {
  const int chunk = blockIdx.x, b = blockIdx.y;
  const int wid = threadIdx.x >> 6, lane = threadIdx.x & 63;
  __shared__ float nsh[4][D];
  __shared__ float sAsh[4];
  float4 p4[4], acc[4];
  const float* pb = p + (size_t)b * D;
  #pragma unroll
  for (int s = 0; s < 4; ++s) {
    p4[s] = *(const float4*)(pb + s * 256 + lane * 4);
    acc[s] = make_float4(0.f, 0.f, 0.f, 0.f);
  }
  const float qd = qdot[b];
  float sAw = 0.f;
  const float* capb = cap + (size_t)b * LSEQ * D;
  for (int i = 0; i < 16; ++i) {
    int c = chunk * 64 + wid + i * 4;
    const float* row = capb + (size_t)c * D;
    float4 r4[4];
    #pragma unroll
    for (int s = 0; s < 4; ++s) r4[s] = *(const float4*)(row + s * 256 + lane * 4);
    float t = 0.f;
    #pragma unroll
    for (int s = 0; s < 4; ++s) {
      t = fmaf(p4[s].x, r4[s].x, t); t = fmaf(p4[s].y, r4[s].y, t);
      t = fmaf(p4[s].z, r4[s].z, t); t = fmaf(p4[s].w, r4[s].w, t);
    }
    #pragma unroll
    for (int off = 32; off; off >>= 1) t += __shfl_xor(t, off);
    float a = SCALE * (t + qd);
    sAw += a;
    #pragma unroll
    for (int s = 0; s < 4; ++s) {
      acc[s].x = fmaf(a, r4[s].x, acc[s].x); acc[s].y = fmaf(a, r4[s].y, acc[s].y);
      acc[s].z = fmaf(a, r4[s].z, acc[s].z); acc[s].w = fmaf(a, r4[s].w, acc[s].w);
    }
  }
  #pragma unroll
  for (int s = 0; s < 4; ++s) *(float4*)&nsh[wid][s * 256 + lane * 4] = acc[s];
  if (lane == 0) sAsh[wid] = sAw;
  __syncthreads();
  const int tid = threadIdx.x;
  float4 v = make_float4(0.f, 0.f, 0.f, 0.f);
  #pragma unroll
  for (int w = 0; w < 4; ++w) {
    float4 x = *(const float4*)&nsh[w][tid * 4];
    v.x += x.x; v.y += x.y; v.z += x.z; v.w += x.w;
  }
  float* nb = nOut + (size_t)b * D + tid * 4;
  atomicAdd(nb + 0, v.x); atomicAdd(nb + 1, v.y);
  atomicAdd(nb + 2, v.z); atomicAdd(nb + 3, v.w);
  if (tid == 0) atomicAdd(&sA[b], sAsh[0] + sAsh[1] + sAsh[2] + sAsh[3]);
}

// Per (chunk,b): online softmax over 64 t's of scores st = SCALE*(w[b].tar[b,t] + cb[b]),
// accumulating sum exp(st-M)*tar[b,t,:]. Outputs per-chunk partial (accP, MP, ZP).
__global__ __launch_bounds__(256) void tar_stream_kernel(
    const float* __restrict__ tar, const float* __restrict__ wv,
    const float* __restrict__ cb, float* __restrict__ accP,
    float* __restrict__ MP, float* __restrict__ ZP) {
  const int chunk = blockIdx.x, b = blockIdx.y;
  const int wid = threadIdx.x >> 6, lane = threadIdx.x & 63;
  __shared__ float ash[4][D];
  __shared__ float msh[4], zsh[4];
  float4 w4[4], acc[4];
  const float* wb = wv + (size_t)b * D;
  #pragma unroll
  for (int s = 0; s < 4; ++s) {
    w4[s] = *(const float4*)(wb + s * 256 + lane * 4);
    acc[s] = make_float4(0.f, 0.f, 0.f, 0.f);
  }
  const float cbb = cb[b];
  float M = -INFINITY, Z = 0.f;
  const float* tb = tar + (size_t)b * LSEQ * D;
  for (int i = 0; i < 16; ++i) {
    int t = chunk * 64 + wid + i * 4;
    const float* row = tb + (size_t)t * D;
    float4 r4[4];
    #pragma unroll
    for (int s = 0; s < 4; ++s) r4[s] = *(const float4*)(row + s * 256 + lane * 4);
    float sc = 0.f;
    #pragma unroll
    for (int s = 0; s < 4; ++s) {
      sc = fmaf(w4[s].x, r4[s].x, sc); sc = fmaf(w4[s].y, r4[s].y, sc);
      sc = fmaf(w4[s].z, r4[s].z, sc); sc = fmaf(w4[s].w, r4[s].w, sc);
    }
    #pragma unroll
    for (int off = 32; off; off >>= 1) sc += __shfl_xor(sc, off);
    float st = SCALE * (sc + cbb);
    if (st <= M) {            // wave-uniform branch
      float e = expf(st - M);
      Z += e;
      #pragma unroll
      for (int s = 0; s < 4; ++s) {
        acc[s].x = fmaf(e, r4[s].x, acc[s].x); acc[s].y = fmaf(e, r4[s].y, acc[s].y);
        acc[s].z = fmaf(e, r4[s].z, acc[s].z); acc[s].w = fmaf(e, r4[s].w, acc[s].w);
      }
    } else {
      float r = expf(M - st); // first iter: exp(-inf)=0
      Z = fmaf(Z, r, 1.f);
      #pragma unroll
      for (int s = 0; s < 4; ++s) {
        acc[s].x = fmaf(acc[s].x, r, r4[s].x); acc[s].y = fmaf(acc[s].y, r, r4[s].y);
        acc[s].z = fmaf(acc[s].z, r, r4[s].z); acc[s].w = fmaf(acc[s].w, r, r4[s].w);
      }
      M = st;
    }
  }
  #pragma unroll
  for (int s = 0; s < 4; ++s) *(float4*)&ash[wid][s * 256 + lane * 4] = acc[s];
  if (lane == 0) { msh[wid] = M; zsh[wid] = Z; }
  __syncthreads();
  const int tid = threadIdx.x;
  float Mb = fmaxf(fmaxf(msh[0], msh[1]), fmaxf(msh[2], msh[3]));
  float e0 = expf(msh[0] - Mb), e1 = expf(msh[1] - Mb);
  float e2 = expf(msh[2] - Mb), e3 = expf(msh[3] - Mb);
  float4 x0 = *(const float4*)&ash[0][tid * 4];
  float4 x1 = *(const float4*)&ash[1][tid * 4];
  float4 x2 = *(const float4*)&ash[2][tid * 4];
  float4 x3 = *(const float4*)&ash[3][tid * 4];
  float4 v;
  v.x = e0 * x0.x + e1 * x1.x + e2 * x2.x + e3 * x3.x;
  v.y = e0 * x0.y + e1 * x1.y + e2 * x2.y + e3 * x3.y;
  v.z = e0 * x0.z + e1 * x1.z + e2 * x2.z + e3 * x3.z;
  v.w = e0 * x0.w + e1 * x1.w + e2 * x2.w + e3 * x3.w;
  *(float4*)(accP + ((size_t)chunk * NB + b) * D + tid * 4) = v;
  if (tid == 0) {
    MP[chunk * NB + b] = Mb;
    ZP[chunk * NB + b] = e0 * zsh[0] + e1 * zsh[1] + e2 * zsh[2] + e3 * zsh[3];
  }
}

// m[b,:] = sum_i exp(M_i-Mg)*accP_i[b,:] / sum_i exp(M_i-Mg)*Z_i
__global__ __launch_bounds__(256) void merge_m_kernel(
    const float* __restrict__ accP, const float* __restrict__ MP,
    const float* __restrict__ ZP, float* __restrict__ m) {
  const int b = blockIdx.x, tid = threadIdx.x;
  float M0 = MP[b], M1 = MP[NB + b], M2 = MP[2 * NB + b], M3 = MP[3 * NB + b];
  float Mg = fmaxf(fmaxf(M0, M1), fmaxf(M2, M3));
  float e0 = expf(M0 - Mg), e1 = expf(M1 - Mg), e2 = expf(M2 - Mg), e3 = expf(M3 - Mg);
  float Zg = e0 * ZP[b] + e1 * ZP[NB + b] + e2 * ZP[2 * NB + b] + e3 * ZP[3 * NB + b];
  float inv = 1.f / Zg;
  float4 x0 = *(const float4*)(accP + ((size_t)0 * NB + b) * D + tid * 4);
  float4 x1 = *(const float4*)(accP + ((size_t)1 * NB + b) * D + tid * 4);
  float4 x2 = *(const float4*)(accP + ((size_t)2 * NB + b) * D + tid * 4);
  float4 x3 = *(const float4*)(accP + ((size_t)3 * NB + b) * D + tid * 4);
  float4 v;
  v.x = (e0 * x0.x + e1 * x1.x + e2 * x2.x + e3 * x3.x) * inv;
  v.y = (e0 * x0.y + e1 * x1.y + e2 * x2.y + e3 * x3.y) * inv;
  v.z = (e0 * x0.z + e1 * x1.z + e2 * x2.z + e3 * x3.z) * inv;
  v.w = (e0 * x0.w + e1 * x1.w + e2 * x2.w + e3 * x3.w) * inv;
  *(float4*)(m + (size_t)b * D + tid * 4) = v;
}

extern "C" void kernel_launch(void* const* d_in, const int* in_sizes, int n_in,
                              void* d_out, int out_size, void* d_ws, size_t ws_size,
                              hipStream_t stream) {
  const float* ref    = (const float*)d_in[0];
  const float* cap    = (const float*)d_in[1];
  const float* tar    = (const float*)d_in[2];
  const float* qr_w   = (const float*)d_in[3];
  const float* qr_b   = (const float*)d_in[4];
  const float* ktxt_w = (const float*)d_in[5];
  const float* ktxt_b = (const float*)d_in[6];
  const float* ktar_w = (const float*)d_in[7];
  const float* ktar_b = (const float*)d_in[8];
  const float* v_w    = (const float*)d_in[9];
  const float* v_b    = (const float*)d_in[10];
  float* out = (float*)d_out;
  float* ws  = (float*)d_ws;

  float* q0   = ws;                 // 131072
  float* p    = ws + 131072;        // 131072
  float* u    = ws + 262144;        // 131072
  float* w    = ws + 393216;        // 131072
  float* n    = ws + 524288;        // 131072
  float* sA   = ws + 655360;        // 128
  float* qdot = ws + 655488;        // 128
  float* cb   = ws + 655616;        // 128
  float* m    = ws + 655744;        // 131072
  float* accP = ws + 786816;        // 524288
  float* MP   = ws + 1311104;       // 512
  float* ZP   = ws + 1311616;       // 512

  // zero atomicAdd targets: q0,p,u,w,n,sA (contiguous) and d_out
  hipMemsetAsync(ws, 0, (size_t)655488 * sizeof(float), stream);
  hipMemsetAsync(out, 0, (size_t)NB * D * sizeof(float), stream);

  dim3 gG(64, 4), bG(256);
  // q0 = ref[:,0,:] @ qr_w^T + qr_b
  gemm128_kernel<0, 1><<<gG, bG, 0, stream>>>(ref, (size_t)LSEQ * D, qr_w, qr_b, nullptr, q0);
  // qdot[b] = q0[b] . ktxt_b
  dot128_kernel<<<NB, 64, 0, stream>>>(q0, ktxt_b, qdot);
  // p = q0 @ ktxt_w
  gemm128_kernel<1, 0><<<gG, bG, 0, stream>>>(q0, (size_t)D, ktxt_w, nullptr, nullptr, p);
  // stream caption: n, sA
  cap_stream_kernel<<<dim3(4, NB), 256, 0, stream>>>(cap, p, qdot, n, sA);
  // u = n @ ktxt_w^T + sA*ktxt_b
  gemm128_kernel<0, 2><<<gG, bG, 0, stream>>>(n, (size_t)D, ktxt_w, ktxt_b, sA, u);
  // cb[b] = u[b] . ktar_b
  dot128_kernel<<<NB, 64, 0, stream>>>(u, ktar_b, cb);
  // w = u @ ktar_w
  gemm128_kernel<1, 0><<<gG, bG, 0, stream>>>(u, (size_t)D, ktar_w, nullptr, nullptr, w);
  // stream target with online softmax partials
  tar_stream_kernel<<<dim3(4, NB), 256, 0, stream>>>(tar, w, cb, accP, MP, ZP);
  // merge to m = attC @ tar
  merge_m_kernel<<<NB, 256, 0, stream>>>(accP, MP, ZP, m);
  // out = m @ v_w^T + v_b
  gemm128_kernel<0, 1><<<gG, bG, 0, stream>>>(m, (size_t)D, v_w, v_b, nullptr, out);
}